// Round 6
// baseline (4160.864 us; speedup 1.0000x reference)
//
#include <hip/hip_runtime.h>
#include <math.h>

#define NROWSQ 32768   // rows per input
#define RTOT   65536   // total rows (mean ++ std)
#define DDIM   512
#define KC     4096

#define CAP    20          // candidate list capacity per row (delayed append -> small)
#define W_ACC  6.0f        // screen window in acc units (dist window = 6/4096 = 1.46e-3)
#define ESCALE 8192.0f     // 2^13, exact; keeps f16(e) out of denormal range

typedef __attribute__((ext_vector_type(8))) _Float16 half8;
typedef __attribute__((ext_vector_type(4))) float f32x4;

// ---- workspace layout (bytes) ----
#define WS_INDS 0               // 65536 * int
#define WS_HIST 262144          // 8192 * int
#define WS_PC1  294912          // 1024 * double
#define WS_PC2  303104          // 1024 * double
#define WS_PKL  311296          // 1024 * double
#define WS_XSQ  319488          // 65536 * float
#define WS_ESQ  581632          // 4096 * float
#define WS_EF16 598016          // 4096*512 * u16 (scaled f16 embedding, TILED layout)
#define WS_EF16_END (598016 + KC * DDIM * 2)

__device__ __forceinline__ uint2 pack4_f16(float4 v, float s) {
    _Float16 h0 = (_Float16)(v.x * s);
    _Float16 h1 = (_Float16)(v.y * s);
    _Float16 h2 = (_Float16)(v.z * s);
    _Float16 h3 = (_Float16)(v.w * s);
    uint2 r;
    r.x = (unsigned int)__builtin_bit_cast(unsigned short, h0)
        | ((unsigned int)__builtin_bit_cast(unsigned short, h1) << 16);
    r.y = (unsigned int)__builtin_bit_cast(unsigned short, h2)
        | ((unsigned int)__builtin_bit_cast(unsigned short, h3) << 16);
    return r;
}

__device__ __forceinline__ unsigned fkey(float f) {
    unsigned u = __float_as_uint(f);
    return u ^ ((unsigned)(((int)u) >> 31) | 0x80000000u);
}
__device__ __forceinline__ float fdecode(unsigned k) {
    return (k & 0x80000000u) ? __uint_as_float(k ^ 0x80000000u) : __uint_as_float(~k);
}

__device__ __forceinline__ void gload_lds16(const void* gsrc, void* ldst) {
    __builtin_amdgcn_global_load_lds(
        (const __attribute__((address_space(1))) unsigned int*)gsrc,
        (__attribute__((address_space(3))) unsigned int*)ldst, 16, 0, 0);
}

// ---------------------------------------------------------------------------
// Kernel 0: per-row sum of squares (f32), one wave per row.
// ---------------------------------------------------------------------------
__global__ __launch_bounds__(256) void rowsq_kernel(const float* __restrict__ src,
                                                    float* __restrict__ dst,
                                                    int nrows)
{
    int row  = blockIdx.x * 4 + (threadIdx.x >> 6);
    int lane = threadIdx.x & 63;
    if (row >= nrows) return;
    const float* p = src + (size_t)row * DDIM;
    float4 v1 = *(const float4*)&p[lane * 4];
    float4 v2 = *(const float4*)&p[256 + lane * 4];
    float s = v1.x*v1.x + v1.y*v1.y + v1.z*v1.z + v1.w*v1.w
            + v2.x*v2.x + v2.y*v2.y + v2.z*v2.z + v2.w*v2.w;
    #pragma unroll
    for (int off = 1; off < 64; off <<= 1) s += __shfl_xor(s, off);
    if (lane == 0) dst[row] = s;
}

// ---------------------------------------------------------------------------
// Kernel 0b: convert embedding to scaled f16 in TILED layout:
// slot(16B) = ct*8192 + chunk*512 + kslot*128 + code
//   where c = ct*128 + code (code row), d = chunk*32 + kslot*8 + 0..7
// ---------------------------------------------------------------------------
__global__ __launch_bounds__(256) void cvt_e_tiled_kernel(const float* __restrict__ emb,
                                                          unsigned short* __restrict__ ef)
{
    int i = blockIdx.x * 256 + threadIdx.x;   // 0..262143
    int c  = i >> 6;          // code 0..4095
    int dg = i & 63;          // 8-half d-group
    const float* p = &emb[(size_t)c * DDIM + dg * 8];
    float4 v0 = *(const float4*)p;
    float4 v1 = *(const float4*)(p + 4);
    uint2 p0 = pack4_f16(v0, ESCALE);
    uint2 p1 = pack4_f16(v1, ESCALE);
    uint4 pk; pk.x = p0.x; pk.y = p0.y; pk.z = p1.x; pk.w = p1.y;
    int ct = c >> 7, code = c & 127, chunk = dg >> 2, kslot = dg & 3;
    size_t slot = (size_t)ct * 8192 + chunk * 512 + kslot * 128 + code;
    *(uint4*)&ef[slot * 8] = pk;
}

// ---------------------------------------------------------------------------
// Kernel 1: A-resident f16 MFMA screen + delayed candidate collect + exact
// rescore. 512 threads (8 waves, wave grid 2 rows x 4 cols).
// B streamed as 512 chunks of (128 codes x 32 d) with NBUF=3 / depth-2
// counted-vmcnt DMA pipeline (issue g+3 after the consume-barrier of g).
// ---------------------------------------------------------------------------
template<bool EF16>
__global__ __launch_bounds__(512, 1) void mfma_argmin_kernel(
    const float* __restrict__ xmean, const float* __restrict__ xstd,
    const float* __restrict__ emb, const unsigned short* __restrict__ ef,
    const float* __restrict__ xsq, const float* __restrict__ esq,
    int* __restrict__ inds)
{
    __shared__ unsigned short As[65536];      // 128KB: A f16, dg-major, XOR-swz
    __shared__ unsigned short Bs[3][4096];    // 3 x 8KB chunk buffers
    __shared__ unsigned int   rowmax[128];
    __shared__ int            ccnt[128];
    __shared__ unsigned short cand[128 * CAP];
    __shared__ unsigned long long best[128];

    const int t    = threadIdx.x;
    const int lane = t & 63;
    const int wid  = t >> 6;                  // 0..7
    const int wr   = wid >> 2, wc = wid & 3;  // wave tile: 64 rows x 32 codes
    const int row0 = blockIdx.x * 128;
    const float* X = (row0 < NROWSQ) ? xmean : xstd;
    const int xrow0 = (row0 < NROWSQ) ? row0 : row0 - NROWSQ;

    if (t < 128) { rowmax[t] = 0u; ccnt[t] = 0; best[t] = ~0ull; }

    // ---- issue DMA for chunks 0,1,2 first (latency hides under A staging) --
    if (EF16) {
        #pragma unroll
        for (int g = 0; g < 3; ++g) {
            const unsigned short* src = ef + ((size_t)g * 512 + wid * 64 + lane) * 8;
            gload_lds16(src, &Bs[g][(wid * 64) * 8]);
        }
    }

    // ---- stage A once: 128 rows x 512 d, f32 -> f16, swizzled ----
    #pragma unroll 4
    for (int s = 0; s < 16; ++s) {
        int i   = t + s * 512;       // 0..8191
        int dg  = i & 63;            // 8-half d-group
        int row = i >> 6;
        const float* xp = &X[(size_t)(xrow0 + row) * DDIM + dg * 8];
        float4 v0 = *(const float4*)xp;
        float4 v1 = *(const float4*)(xp + 4);
        uint2 p0 = pack4_f16(v0, 1.0f);
        uint2 p1 = pack4_f16(v1, 1.0f);
        uint4 pk; pk.x = p0.x; pk.y = p0.y; pk.z = p1.x; pk.w = p1.y;
        int a16 = dg * 128 + (row ^ (dg & 7));
        *(uint4*)&As[a16 * 8] = pk;
    }

    f32x4 accp[4][2];                // previous tile's finished accs
    #pragma unroll
    for (int fr = 0; fr < 4; ++fr)
        #pragma unroll
        for (int fc = 0; fc < 2; ++fc)
            accp[fr][fc] = (f32x4)(0.0f);

    for (int ct = 0; ct < 32; ++ct) {
        f32x4 acc[4][2];
        #pragma unroll
        for (int fr = 0; fr < 4; ++fr)
            #pragma unroll
            for (int fc = 0; fc < 2; ++fc)
                acc[fr][fc] = (f32x4)(0.0f);

        for (int c = 0; c < 16; ++c) {
            const int g = ct * 16 + c;
            const unsigned short* bbuf = &Bs[g % 3][0];

            if (EF16) {
                // wait: chunk g landed (per-wave; 2 newer may stay in flight)
                if (g >= 510) { asm volatile("s_waitcnt vmcnt(0)" ::: "memory"); }
                else          { asm volatile("s_waitcnt vmcnt(2)" ::: "memory"); }
                __builtin_amdgcn_sched_barrier(0);
                __builtin_amdgcn_s_barrier();     // all waves' parts of g landed
                __builtin_amdgcn_sched_barrier(0);
            } else {
                __syncthreads();
                {
                    int kslot = t >> 7, code = t & 127;     // slot 0..511
                    int dg = c * 4 + kslot;
                    const float* p = &emb[(size_t)(ct * 128 + code) * DDIM + dg * 8];
                    float4 v0 = *(const float4*)p;
                    float4 v1 = *(const float4*)(p + 4);
                    uint2 p0 = pack4_f16(v0, ESCALE);
                    uint2 p1 = pack4_f16(v1, ESCALE);
                    uint4 pk; pk.x = p0.x; pk.y = p0.y; pk.z = p1.x; pk.w = p1.y;
                    *(uint4*)&Bs[0][t * 8] = pk;
                }
                __syncthreads();
                bbuf = &Bs[0][0];
            }

            // ---- compute chunk: 6 frag reads + 8 MFMA per wave ----
            half8 bfrag[2], afrag[4];
            #pragma unroll
            for (int fc = 0; fc < 2; ++fc) {
                int code = wc * 32 + fc * 16 + (lane & 15);
                int b16  = (lane >> 4) * 128 + code;
                bfrag[fc] = *(const half8*)&bbuf[b16 * 8];
            }
            #pragma unroll
            for (int fr = 0; fr < 4; ++fr) {
                int ra = wr * 64 + fr * 16 + (lane & 15);
                int dg = c * 4 + (lane >> 4);
                int a16 = dg * 128 + (ra ^ (dg & 7));
                afrag[fr] = *(const half8*)&As[a16 * 8];
            }
            #pragma unroll
            for (int fr = 0; fr < 4; ++fr)
                #pragma unroll
                for (int fc = 0; fc < 2; ++fc)
                    acc[fr][fc] = __builtin_amdgcn_mfma_f32_16x16x32_f16(
                        afrag[fr], bfrag[fc], acc[fr][fc], 0, 0, 0);

            if (EF16) {
                // consume-barrier: all waves done reading chunk g ->
                // buffer (g+3)%3 == g%3 is safe to overwrite
                asm volatile("s_waitcnt lgkmcnt(0)" ::: "memory");
                __builtin_amdgcn_sched_barrier(0);
                __builtin_amdgcn_s_barrier();
                __builtin_amdgcn_sched_barrier(0);
                if (g + 3 < 512) {
                    const int gi = g + 3;
                    const unsigned short* src = ef + ((size_t)gi * 512 + wid * 64 + lane) * 8;
                    gload_lds16(src, &Bs[gi % 3][(wid * 64) * 8]);
                }
            }
        }

        // ---- update running row-max with THIS tile's accs ----
        #pragma unroll
        for (int fr = 0; fr < 4; ++fr) {
            #pragma unroll
            for (int q = 0; q < 4; ++q) {
                float m = fmaxf(acc[fr][0][q], acc[fr][1][q]);
                int r = wr * 64 + fr * 16 + (lane >> 4) * 4 + q;
                unsigned k = fkey(m);
                if (k > rowmax[r]) atomicMax(&rowmax[r], k);
            }
        }
        asm volatile("s_waitcnt lgkmcnt(0)" ::: "memory");
        __builtin_amdgcn_sched_barrier(0);
        __builtin_amdgcn_s_barrier();
        __builtin_amdgcn_sched_barrier(0);

        // ---- delayed append: PREVIOUS tile's candidates vs tighter max ----
        if (ct > 0) {
            const int pct = ct - 1;
            #pragma unroll
            for (int fr = 0; fr < 4; ++fr) {
                #pragma unroll
                for (int q = 0; q < 4; ++q) {
                    int r = wr * 64 + fr * 16 + (lane >> 4) * 4 + q;
                    float thr = fdecode(rowmax[r]) - W_ACC;
                    #pragma unroll
                    for (int fc = 0; fc < 2; ++fc) {
                        if (accp[fr][fc][q] >= thr) {
                            int code = pct * 128 + wc * 32 + fc * 16 + (lane & 15);
                            int p = atomicAdd(&ccnt[r], 1);
                            if (p < CAP) cand[r * CAP + p] = (unsigned short)code;
                        }
                    }
                }
            }
        }
        #pragma unroll
        for (int fr = 0; fr < 4; ++fr)
            #pragma unroll
            for (int fc = 0; fc < 2; ++fc)
                accp[fr][fc] = acc[fr][fc];
    }

    // ---- append LAST tile (rowmax is final now) ----
    {
        const int pct = 31;
        #pragma unroll
        for (int fr = 0; fr < 4; ++fr) {
            #pragma unroll
            for (int q = 0; q < 4; ++q) {
                int r = wr * 64 + fr * 16 + (lane >> 4) * 4 + q;
                float thr = fdecode(rowmax[r]) - W_ACC;
                #pragma unroll
                for (int fc = 0; fc < 2; ++fc) {
                    if (accp[fr][fc][q] >= thr) {
                        int code = pct * 128 + wc * 32 + fc * 16 + (lane & 15);
                        int p = atomicAdd(&ccnt[r], 1);
                        if (p < CAP) cand[r * CAP + p] = (unsigned short)code;
                    }
                }
            }
        }
    }
    __syncthreads();

    // ---- exact f32 rescore of candidates (replicates round-1 fmaf chain) ----
    for (int e = t; e < 128 * CAP; e += 512) {
        int r = e / CAP, s = e - r * CAP;
        int cnt = ccnt[r]; if (cnt > CAP) cnt = CAP;
        if (s < cnt) {
            int c = cand[r * CAP + s];
            const float* xp = X   + (size_t)(xrow0 + r) * DDIM;
            const float* ep = emb + (size_t)c * DDIM;
            float acc2 = 0.0f;
            for (int d = 0; d < DDIM; d += 4) {
                float4 xv = *(const float4*)&xp[d];
                float4 ev = *(const float4*)&ep[d];
                acc2 = fmaf(xv.x, ev.x, acc2);
                acc2 = fmaf(xv.y, ev.y, acc2);
                acc2 = fmaf(xv.z, ev.z, acc2);
                acc2 = fmaf(xv.w, ev.w, acc2);
            }
            float dist = (xsq[row0 + r] + esq[c]) - 2.0f * acc2;
            unsigned long long key =
                ((unsigned long long)__float_as_uint(dist) << 32) | (unsigned)c;
            atomicMin(&best[r], key);
        }
    }
    __syncthreads();

    // ---- overflow fallback: full-row exact rescan (expected: never) ----
    for (int r = 0; r < 128; ++r) {
        if (ccnt[r] > CAP) {
            const float* xp = X + (size_t)(xrow0 + r) * DDIM;
            float xse = xsq[row0 + r];
            for (int c = t; c < KC; c += 512) {
                const float* ep = emb + (size_t)c * DDIM;
                float acc2 = 0.0f;
                #pragma unroll 8
                for (int d = 0; d < DDIM; d += 4) {
                    float4 xv = *(const float4*)&xp[d];
                    float4 ev = *(const float4*)&ep[d];
                    acc2 = fmaf(xv.x, ev.x, acc2);
                    acc2 = fmaf(xv.y, ev.y, acc2);
                    acc2 = fmaf(xv.z, ev.z, acc2);
                    acc2 = fmaf(xv.w, ev.w, acc2);
                }
                float dist = (xse + esq[c]) - 2.0f * acc2;
                unsigned long long key =
                    ((unsigned long long)__float_as_uint(dist) << 32) | (unsigned)c;
                atomicMin(&best[r], key);
            }
        }
    }
    __syncthreads();
    if (t < 128) inds[row0 + t] = (int)(unsigned)(best[t] & 0xffffffffull);
}

// ---------------------------------------------------------------------------
// Kernel 2: gather quantized rows + commitment/KL partials + hist. (unchanged)
// ---------------------------------------------------------------------------
__global__ __launch_bounds__(256) void gather_stats_kernel(
    const float* __restrict__ xmean, const float* __restrict__ xstd,
    const float* __restrict__ emb, const int* __restrict__ inds,
    float* __restrict__ out0, float* __restrict__ out1,
    int* __restrict__ hist,
    double* __restrict__ pc1, double* __restrict__ pc2, double* __restrict__ pkl)
{
    const int blk  = blockIdx.x;
    const int w    = threadIdx.x >> 6;
    const int lane = threadIdx.x & 63;

    float c1 = 0.0f, c2 = 0.0f, kls = 0.0f;

    for (int j = 0; j < 8; j++) {
        int n  = blk * 32 + j * 4 + w;
        int im = inds[n];
        int is = inds[NROWSQ + n];
        if (lane == 0) {
            atomicAdd(&hist[im], 1);
            atomicAdd(&hist[KC + is], 1);
        }
        const float* em = emb  + (size_t)im * DDIM;
        const float* es = emb  + (size_t)is * DDIM;
        const float* xm = xmean + (size_t)n * DDIM;
        const float* xv = xstd  + (size_t)n * DDIM;

        float t1 = 0.0f, t2 = 0.0f;
        float pp = 1.0f, pq = 1.0f;

        #pragma unroll
        for (int half = 0; half < 2; half++) {
            int d = half * 256 + lane * 4;
            float4 q4  = *(const float4*)&em[d];
            float4 m4  = *(const float4*)&xm[d];
            float4 qs4 = *(const float4*)&es[d];
            float4 s4  = *(const float4*)&xv[d];
            float qa[4] = {q4.x, q4.y, q4.z, q4.w};
            float ma[4] = {m4.x, m4.y, m4.z, m4.w};
            float qb[4] = {qs4.x, qs4.y, qs4.z, qs4.w};
            float sa[4] = {s4.x, s4.y, s4.z, s4.w};
            float o0[4], o1[4];
            #pragma unroll
            for (int u = 0; u < 4; u++) {
                float q = qa[u], m = ma[u], s = sa[u], qq = qb[u];
                o0[u] = m + (q - m);
                o1[u] = qq;
                float du = q - m;
                c1 += du * du;
                float dsv = qq - s; c2 += dsv * dsv;
                float sp = s * s, sq = qq * qq;
                float iq = 1.0f / sq;
                t1 += sp * iq;
                t2 += du * du * iq;
                pp *= sp; pq *= sq;
            }
            *(float4*)&out0[(size_t)n * DDIM + d] = make_float4(o0[0], o0[1], o0[2], o0[3]);
            *(float4*)&out1[(size_t)n * DDIM + d] = make_float4(o1[0], o1[1], o1[2], o1[3]);
        }

        #pragma unroll
        for (int off = 1; off < 64; off <<= 1) {
            t1 += __shfl_xor(t1, off);
            t2 += __shfl_xor(t2, off);
            pp *= __shfl_xor(pp, off);
            pq *= __shfl_xor(pq, off);
        }
        if (lane == 0) {
            float term4 = logf(pq + 1e-8f) - logf(pp + 1e-8f);
            float kl = 0.5f * (t1 + t2 - (float)DDIM + term4);
            float klc = kl < 0.0f ? 0.0f : (kl > 10.0f ? 10.0f : kl);
            kls += klc;
        }
    }

    #pragma unroll
    for (int off = 1; off < 64; off <<= 1) {
        c1 += __shfl_xor(c1, off);
        c2 += __shfl_xor(c2, off);
    }
    __shared__ double sc1[4], sc2[4], skl[4];
    if (lane == 0) { sc1[w] = (double)c1; sc2[w] = (double)c2; skl[w] = (double)kls; }
    __syncthreads();
    if (threadIdx.x == 0) {
        pc1[blk] = sc1[0] + sc1[1] + sc1[2] + sc1[3];
        pc2[blk] = sc2[0] + sc2[1] + sc2[2] + sc2[3];
        pkl[blk] = skl[0] + skl[1] + skl[2] + skl[3];
    }
}

// ---------------------------------------------------------------------------
// Kernel 3: finalize scalars. (unchanged)
// ---------------------------------------------------------------------------
__global__ __launch_bounds__(256) void finalize_kernel(
    const int* __restrict__ hist,
    const double* __restrict__ pc1, const double* __restrict__ pc2,
    const double* __restrict__ pkl,
    float* __restrict__ out)
{
    int t = threadIdx.x;
    int w = t >> 6, lane = t & 63;

    double a = 0.0, b = 0.0, c = 0.0;
    for (int i = t; i < 1024; i += 256) { a += pc1[i]; b += pc2[i]; c += pkl[i]; }

    float hm = 0.0f, hs = 0.0f;
    for (int k = t; k < KC; k += 256) {
        float p  = (float)hist[k]      * (1.0f / 32768.0f);
        hm += p * logf(p + 1e-10f);
        float p2 = (float)hist[KC + k] * (1.0f / 32768.0f);
        hs += p2 * logf(p2 + 1e-10f);
    }

    #pragma unroll
    for (int off = 1; off < 64; off <<= 1) {
        a  += __shfl_xor(a, off);
        b  += __shfl_xor(b, off);
        c  += __shfl_xor(c, off);
        hm += __shfl_xor(hm, off);
        hs += __shfl_xor(hs, off);
    }
    __shared__ double sa[4], sb[4], sc[4];
    __shared__ float  sm[4], ss[4];
    if (lane == 0) { sa[w] = a; sb[w] = b; sc[w] = c; sm[w] = hm; ss[w] = hs; }
    __syncthreads();
    if (t == 0) {
        double A = sa[0] + sa[1] + sa[2] + sa[3];
        double B = sb[0] + sb[1] + sb[2] + sb[3];
        double C = sc[0] + sc[1] + sc[2] + sc[3];
        float HM = sm[0] + sm[1] + sm[2] + sm[3];
        float HS = ss[0] + ss[1] + ss[2] + ss[3];
        float mean1 = (float)(A * (1.0 / 16777216.0));
        float mean2 = (float)(B * (1.0 / 16777216.0));
        float commitment = mean1 + mean2;
        float el = (float)(C * (1.0 / 32768.0));
        out[33554432] = commitment * 0.25f + el;   // vq_loss
        out[33554433] = expf(-HM);                 // perplexity_mean
        out[33554434] = expf(-HS);                 // perplexity_std
    }
}

// ---------------------------------------------------------------------------
extern "C" void kernel_launch(void* const* d_in, const int* in_sizes, int n_in,
                              void* d_out, int out_size, void* d_ws, size_t ws_size,
                              hipStream_t stream)
{
    const float* xmean = (const float*)d_in[0];
    const float* xstd  = (const float*)d_in[1];
    const float* emb   = (const float*)d_in[2];
    float* out = (float*)d_out;
    char*  ws  = (char*)d_ws;

    int*    inds = (int*)(ws + WS_INDS);
    int*    hist = (int*)(ws + WS_HIST);
    double* pc1  = (double*)(ws + WS_PC1);
    double* pc2  = (double*)(ws + WS_PC2);
    double* pkl  = (double*)(ws + WS_PKL);
    float*  xsq  = (float*)(ws + WS_XSQ);
    float*  esq  = (float*)(ws + WS_ESQ);
    unsigned short* ef16 = (unsigned short*)(ws + WS_EF16);

    const bool use_ef16 = (ws_size >= (size_t)WS_EF16_END);

    hipMemsetAsync(hist, 0, 2 * KC * sizeof(int), stream);

    rowsq_kernel<<<NROWSQ / 4, 256, 0, stream>>>(xmean, xsq, NROWSQ);
    rowsq_kernel<<<NROWSQ / 4, 256, 0, stream>>>(xstd, xsq + NROWSQ, NROWSQ);
    rowsq_kernel<<<KC / 4, 256, 0, stream>>>(emb, esq, KC);

    if (use_ef16) {
        cvt_e_tiled_kernel<<<KC * DDIM / 8 / 256, 256, 0, stream>>>(emb, ef16);
        mfma_argmin_kernel<true><<<RTOT / 128, 512, 0, stream>>>(
            xmean, xstd, emb, ef16, xsq, esq, inds);
    } else {
        mfma_argmin_kernel<false><<<RTOT / 128, 512, 0, stream>>>(
            xmean, xstd, emb, ef16, xsq, esq, inds);
    }

    gather_stats_kernel<<<1024, 256, 0, stream>>>(xmean, xstd, emb, inds,
                                                  out, out + (size_t)NROWSQ * DDIM,
                                                  hist, pc1, pc2, pkl);

    finalize_kernel<<<1, 256, 0, stream>>>(hist, pc1, pc2, pkl, out);
}

// Round 7
// 1357.256 us; speedup vs baseline: 3.0656x; 3.0656x over previous
//
#include <hip/hip_runtime.h>
#include <math.h>

#define NROWSQ 32768   // rows per input
#define RTOT   65536   // total rows (mean ++ std)
#define DDIM   512
#define KC     4096

#define CAP    32          // candidate list capacity per row
#define W_ACC  6.0f        // screen window in acc units (dist window = 6/4096 = 1.46e-3)
#define ESCALE 8192.0f     // 2^13, exact; keeps f16(e) out of denormal range

typedef __attribute__((ext_vector_type(8))) _Float16 half8;
typedef __attribute__((ext_vector_type(4))) float f32x4;

// ---- workspace layout (bytes) ----
#define WS_INDS 0               // 65536 * int
#define WS_HIST 262144          // 8192 * int
#define WS_PC1  294912          // 1024 * double
#define WS_PC2  303104          // 1024 * double
#define WS_PKL  311296          // 1024 * double
#define WS_XSQ  319488          // 65536 * float
#define WS_ESQ  581632          // 4096 * float
#define WS_EF16 598016          // 4096*512 * u16 (scaled f16 embedding, TILED layout)
#define WS_EF16_END (598016 + KC * DDIM * 2)

__device__ __forceinline__ uint2 pack4_f16(float4 v, float s) {
    _Float16 h0 = (_Float16)(v.x * s);
    _Float16 h1 = (_Float16)(v.y * s);
    _Float16 h2 = (_Float16)(v.z * s);
    _Float16 h3 = (_Float16)(v.w * s);
    uint2 r;
    r.x = (unsigned int)__builtin_bit_cast(unsigned short, h0)
        | ((unsigned int)__builtin_bit_cast(unsigned short, h1) << 16);
    r.y = (unsigned int)__builtin_bit_cast(unsigned short, h2)
        | ((unsigned int)__builtin_bit_cast(unsigned short, h3) << 16);
    return r;
}

__device__ __forceinline__ unsigned fkey(float f) {
    unsigned u = __float_as_uint(f);
    return u ^ ((unsigned)(((int)u) >> 31) | 0x80000000u);
}
__device__ __forceinline__ float fdecode(unsigned k) {
    return (k & 0x80000000u) ? __uint_as_float(k ^ 0x80000000u) : __uint_as_float(~k);
}

// ---------------------------------------------------------------------------
// Kernel 0: per-row sum of squares (f32), one wave per row.
// ---------------------------------------------------------------------------
__global__ __launch_bounds__(256) void rowsq_kernel(const float* __restrict__ src,
                                                    float* __restrict__ dst,
                                                    int nrows)
{
    int row  = blockIdx.x * 4 + (threadIdx.x >> 6);
    int lane = threadIdx.x & 63;
    if (row >= nrows) return;
    const float* p = src + (size_t)row * DDIM;
    float4 v1 = *(const float4*)&p[lane * 4];
    float4 v2 = *(const float4*)&p[256 + lane * 4];
    float s = v1.x*v1.x + v1.y*v1.y + v1.z*v1.z + v1.w*v1.w
            + v2.x*v2.x + v2.y*v2.y + v2.z*v2.z + v2.w*v2.w;
    #pragma unroll
    for (int off = 1; off < 64; off <<= 1) s += __shfl_xor(s, off);
    if (lane == 0) dst[row] = s;
}

// ---------------------------------------------------------------------------
// Kernel 0b: convert embedding to scaled f16 in TILED layout:
// slot(16B) = ct*8192 + chunk*512 + kslot*128 + code
//   where c = ct*128 + code (code row), d = chunk*32 + kslot*8 + 0..7
// ---------------------------------------------------------------------------
__global__ __launch_bounds__(256) void cvt_e_tiled_kernel(const float* __restrict__ emb,
                                                          unsigned short* __restrict__ ef)
{
    int i = blockIdx.x * 256 + threadIdx.x;   // 0..262143
    int c  = i >> 6;          // code 0..4095
    int dg = i & 63;          // 8-half d-group
    const float* p = &emb[(size_t)c * DDIM + dg * 8];
    float4 v0 = *(const float4*)p;
    float4 v1 = *(const float4*)(p + 4);
    uint2 p0 = pack4_f16(v0, ESCALE);
    uint2 p1 = pack4_f16(v1, ESCALE);
    uint4 pk; pk.x = p0.x; pk.y = p0.y; pk.z = p1.x; pk.w = p1.y;
    int ct = c >> 7, code = c & 127, chunk = dg >> 2, kslot = dg & 3;
    size_t slot = (size_t)ct * 8192 + chunk * 512 + kslot * 128 + code;
    *(uint4*)&ef[slot * 8] = pk;
}

// ---------------------------------------------------------------------------
// Kernel 1: A-resident (LDS) f16 MFMA screen, B direct global->VGPR,
// NO barriers / NO inline asm in the hot loop. 512 threads, wave grid 2x4.
// Delayed candidate append + exact f32 rescore (bit-identical inds).
// ---------------------------------------------------------------------------
template<bool EF16>
__global__ __launch_bounds__(512, 1) void mfma_argmin_kernel(
    const float* __restrict__ xmean, const float* __restrict__ xstd,
    const float* __restrict__ emb, const unsigned short* __restrict__ ef,
    const float* __restrict__ xsq, const float* __restrict__ esq,
    int* __restrict__ inds)
{
    __shared__ unsigned short As[65536];      // 128KB: A f16, dg-major, XOR-swz
    __shared__ unsigned int   rowmax[128];
    __shared__ int            ccnt[128];
    __shared__ unsigned short cand[128 * CAP];
    __shared__ unsigned long long best[128];

    const int t    = threadIdx.x;
    const int lane = t & 63;
    const int wid  = t >> 6;                  // 0..7
    const int wr   = wid >> 2, wc = wid & 3;  // wave tile: 64 rows x 32 codes
    const int row0 = blockIdx.x * 128;
    const float* X = (row0 < NROWSQ) ? xmean : xstd;
    const int xrow0 = (row0 < NROWSQ) ? row0 : row0 - NROWSQ;

    if (t < 128) { rowmax[t] = 0u; ccnt[t] = 0; best[t] = ~0ull; }

    // ---- stage A once: 128 rows x 512 d, f32 -> f16, swizzled ----
    #pragma unroll 4
    for (int s = 0; s < 16; ++s) {
        int i   = t + s * 512;       // 0..8191
        int dg  = i & 63;            // 8-half d-group
        int row = i >> 6;
        const float* xp = &X[(size_t)(xrow0 + row) * DDIM + dg * 8];
        float4 v0 = *(const float4*)xp;
        float4 v1 = *(const float4*)(xp + 4);
        uint2 p0 = pack4_f16(v0, 1.0f);
        uint2 p1 = pack4_f16(v1, 1.0f);
        uint4 pk; pk.x = p0.x; pk.y = p0.y; pk.z = p1.x; pk.w = p1.y;
        int a16 = dg * 128 + (row ^ (dg & 7));
        *(uint4*)&As[a16 * 8] = pk;
    }
    __syncthreads();

    // B-frag base slot (16B units) within a chunk, for this lane:
    // slot = kslot*128 + code ; code = wc*32 + fc*16 + (lane&15)
    const int bo0 = ((lane >> 4) * 128) + wc * 32 + (lane & 15);   // fc=0
    const uint4* __restrict__ bptr = (const uint4*)ef;

    f32x4 accp[4][2];                // previous tile's finished accs
    #pragma unroll
    for (int fr = 0; fr < 4; ++fr)
        #pragma unroll
        for (int fc = 0; fc < 2; ++fc)
            accp[fr][fc] = (f32x4)(0.0f);

    // ---- preload chunk 0 B-frags ----
    uint4 bn0, bn1;
    if (EF16) {
        bn0 = bptr[bo0];
        bn1 = bptr[bo0 + 16];
    }

    for (int ct = 0; ct < 32; ++ct) {
        f32x4 acc[4][2];
        #pragma unroll
        for (int fr = 0; fr < 4; ++fr)
            #pragma unroll
            for (int fc = 0; fc < 2; ++fc)
                acc[fr][fc] = (f32x4)(0.0f);

        #pragma unroll 2
        for (int c = 0; c < 16; ++c) {
            const int g = ct * 16 + c;
            half8 bfrag[2];

            if (EF16) {
                bfrag[0] = __builtin_bit_cast(half8, bn0);
                bfrag[1] = __builtin_bit_cast(half8, bn1);
                int gn = g + 1; if (gn > 511) gn = 511;   // branchless tail
                bn0 = bptr[(size_t)gn * 512 + bo0];
                bn1 = bptr[(size_t)gn * 512 + bo0 + 16];
            } else {
                // fallback: direct load + convert from f32 emb
                #pragma unroll
                for (int fc = 0; fc < 2; ++fc) {
                    int code = ct * 128 + wc * 32 + fc * 16 + (lane & 15);
                    const float* p = &emb[(size_t)code * DDIM + c * 32 + (lane >> 4) * 8];
                    float4 v0 = *(const float4*)p;
                    float4 v1 = *(const float4*)(p + 4);
                    uint2 p0 = pack4_f16(v0, ESCALE);
                    uint2 p1 = pack4_f16(v1, ESCALE);
                    uint4 pk; pk.x = p0.x; pk.y = p0.y; pk.z = p1.x; pk.w = p1.y;
                    bfrag[fc] = __builtin_bit_cast(half8, pk);
                }
            }

            half8 afrag[4];
            #pragma unroll
            for (int fr = 0; fr < 4; ++fr) {
                int ra = wr * 64 + fr * 16 + (lane & 15);
                int dg = c * 4 + (lane >> 4);
                int a16 = dg * 128 + (ra ^ (dg & 7));
                afrag[fr] = *(const half8*)&As[a16 * 8];
            }
            #pragma unroll
            for (int fr = 0; fr < 4; ++fr)
                #pragma unroll
                for (int fc = 0; fc < 2; ++fc)
                    acc[fr][fc] = __builtin_amdgcn_mfma_f32_16x16x32_f16(
                        afrag[fr], bfrag[fc], acc[fr][fc], 0, 0, 0);
        }

        // ---- update running row-max with THIS tile's accs (no barrier:
        //      races only make append thresholds more permissive -> sound) ----
        #pragma unroll
        for (int fr = 0; fr < 4; ++fr) {
            #pragma unroll
            for (int q = 0; q < 4; ++q) {
                float m = fmaxf(acc[fr][0][q], acc[fr][1][q]);
                int r = wr * 64 + fr * 16 + (lane >> 4) * 4 + q;
                unsigned k = fkey(m);
                if (k > rowmax[r]) atomicMax(&rowmax[r], k);
            }
        }

        // ---- delayed append: PREVIOUS tile's candidates vs tighter max ----
        if (ct > 0) {
            const int pct = ct - 1;
            #pragma unroll
            for (int fr = 0; fr < 4; ++fr) {
                #pragma unroll
                for (int q = 0; q < 4; ++q) {
                    int r = wr * 64 + fr * 16 + (lane >> 4) * 4 + q;
                    float thr = fdecode(rowmax[r]) - W_ACC;
                    #pragma unroll
                    for (int fc = 0; fc < 2; ++fc) {
                        if (accp[fr][fc][q] >= thr) {
                            int code = pct * 128 + wc * 32 + fc * 16 + (lane & 15);
                            int p = atomicAdd(&ccnt[r], 1);
                            if (p < CAP) cand[r * CAP + p] = (unsigned short)code;
                        }
                    }
                }
            }
        }
        #pragma unroll
        for (int fr = 0; fr < 4; ++fr)
            #pragma unroll
            for (int fc = 0; fc < 2; ++fc)
                accp[fr][fc] = acc[fr][fc];
    }

    // ---- append LAST tile (rowmax is final now) ----
    {
        const int pct = 31;
        #pragma unroll
        for (int fr = 0; fr < 4; ++fr) {
            #pragma unroll
            for (int q = 0; q < 4; ++q) {
                int r = wr * 64 + fr * 16 + (lane >> 4) * 4 + q;
                float thr = fdecode(rowmax[r]) - W_ACC;
                #pragma unroll
                for (int fc = 0; fc < 2; ++fc) {
                    if (accp[fr][fc][q] >= thr) {
                        int code = pct * 128 + wc * 32 + fc * 16 + (lane & 15);
                        int p = atomicAdd(&ccnt[r], 1);
                        if (p < CAP) cand[r * CAP + p] = (unsigned short)code;
                    }
                }
            }
        }
    }
    __syncthreads();

    // ---- exact f32 rescore of candidates (replicates round-1 fmaf chain) ----
    for (int e = t; e < 128 * CAP; e += 512) {
        int r = e >> 5, s = e & (CAP - 1);
        int cnt = ccnt[r]; if (cnt > CAP) cnt = CAP;
        if (s < cnt) {
            int c = cand[r * CAP + s];
            const float* xp = X   + (size_t)(xrow0 + r) * DDIM;
            const float* ep = emb + (size_t)c * DDIM;
            float acc2 = 0.0f;
            for (int d = 0; d < DDIM; d += 4) {
                float4 xv = *(const float4*)&xp[d];
                float4 ev = *(const float4*)&ep[d];
                acc2 = fmaf(xv.x, ev.x, acc2);
                acc2 = fmaf(xv.y, ev.y, acc2);
                acc2 = fmaf(xv.z, ev.z, acc2);
                acc2 = fmaf(xv.w, ev.w, acc2);
            }
            float dist = (xsq[row0 + r] + esq[c]) - 2.0f * acc2;
            unsigned long long key =
                ((unsigned long long)__float_as_uint(dist) << 32) | (unsigned)c;
            atomicMin(&best[r], key);
        }
    }
    __syncthreads();

    // ---- overflow fallback: full-row exact rescan (expected: never) ----
    for (int r = 0; r < 128; ++r) {
        if (ccnt[r] > CAP) {
            const float* xp = X + (size_t)(xrow0 + r) * DDIM;
            float xse = xsq[row0 + r];
            for (int c = t; c < KC; c += 512) {
                const float* ep = emb + (size_t)c * DDIM;
                float acc2 = 0.0f;
                #pragma unroll 8
                for (int d = 0; d < DDIM; d += 4) {
                    float4 xv = *(const float4*)&xp[d];
                    float4 ev = *(const float4*)&ep[d];
                    acc2 = fmaf(xv.x, ev.x, acc2);
                    acc2 = fmaf(xv.y, ev.y, acc2);
                    acc2 = fmaf(xv.z, ev.z, acc2);
                    acc2 = fmaf(xv.w, ev.w, acc2);
                }
                float dist = (xse + esq[c]) - 2.0f * acc2;
                unsigned long long key =
                    ((unsigned long long)__float_as_uint(dist) << 32) | (unsigned)c;
                atomicMin(&best[r], key);
            }
        }
    }
    __syncthreads();
    if (t < 128) inds[row0 + t] = (int)(unsigned)(best[t] & 0xffffffffull);
}

// ---------------------------------------------------------------------------
// Kernel 2: gather quantized rows + commitment/KL partials + hist. (unchanged)
// ---------------------------------------------------------------------------
__global__ __launch_bounds__(256) void gather_stats_kernel(
    const float* __restrict__ xmean, const float* __restrict__ xstd,
    const float* __restrict__ emb, const int* __restrict__ inds,
    float* __restrict__ out0, float* __restrict__ out1,
    int* __restrict__ hist,
    double* __restrict__ pc1, double* __restrict__ pc2, double* __restrict__ pkl)
{
    const int blk  = blockIdx.x;
    const int w    = threadIdx.x >> 6;
    const int lane = threadIdx.x & 63;

    float c1 = 0.0f, c2 = 0.0f, kls = 0.0f;

    for (int j = 0; j < 8; j++) {
        int n  = blk * 32 + j * 4 + w;
        int im = inds[n];
        int is = inds[NROWSQ + n];
        if (lane == 0) {
            atomicAdd(&hist[im], 1);
            atomicAdd(&hist[KC + is], 1);
        }
        const float* em = emb  + (size_t)im * DDIM;
        const float* es = emb  + (size_t)is * DDIM;
        const float* xm = xmean + (size_t)n * DDIM;
        const float* xv = xstd  + (size_t)n * DDIM;

        float t1 = 0.0f, t2 = 0.0f;
        float pp = 1.0f, pq = 1.0f;

        #pragma unroll
        for (int half = 0; half < 2; half++) {
            int d = half * 256 + lane * 4;
            float4 q4  = *(const float4*)&em[d];
            float4 m4  = *(const float4*)&xm[d];
            float4 qs4 = *(const float4*)&es[d];
            float4 s4  = *(const float4*)&xv[d];
            float qa[4] = {q4.x, q4.y, q4.z, q4.w};
            float ma[4] = {m4.x, m4.y, m4.z, m4.w};
            float qb[4] = {qs4.x, qs4.y, qs4.z, qs4.w};
            float sa[4] = {s4.x, s4.y, s4.z, s4.w};
            float o0[4], o1[4];
            #pragma unroll
            for (int u = 0; u < 4; u++) {
                float q = qa[u], m = ma[u], s = sa[u], qq = qb[u];
                o0[u] = m + (q - m);
                o1[u] = qq;
                float du = q - m;
                c1 += du * du;
                float dsv = qq - s; c2 += dsv * dsv;
                float sp = s * s, sq = qq * qq;
                float iq = 1.0f / sq;
                t1 += sp * iq;
                t2 += du * du * iq;
                pp *= sp; pq *= sq;
            }
            *(float4*)&out0[(size_t)n * DDIM + d] = make_float4(o0[0], o0[1], o0[2], o0[3]);
            *(float4*)&out1[(size_t)n * DDIM + d] = make_float4(o1[0], o1[1], o1[2], o1[3]);
        }

        #pragma unroll
        for (int off = 1; off < 64; off <<= 1) {
            t1 += __shfl_xor(t1, off);
            t2 += __shfl_xor(t2, off);
            pp *= __shfl_xor(pp, off);
            pq *= __shfl_xor(pq, off);
        }
        if (lane == 0) {
            float term4 = logf(pq + 1e-8f) - logf(pp + 1e-8f);
            float kl = 0.5f * (t1 + t2 - (float)DDIM + term4);
            float klc = kl < 0.0f ? 0.0f : (kl > 10.0f ? 10.0f : kl);
            kls += klc;
        }
    }

    #pragma unroll
    for (int off = 1; off < 64; off <<= 1) {
        c1 += __shfl_xor(c1, off);
        c2 += __shfl_xor(c2, off);
    }
    __shared__ double sc1[4], sc2[4], skl[4];
    if (lane == 0) { sc1[w] = (double)c1; sc2[w] = (double)c2; skl[w] = (double)kls; }
    __syncthreads();
    if (threadIdx.x == 0) {
        pc1[blk] = sc1[0] + sc1[1] + sc1[2] + sc1[3];
        pc2[blk] = sc2[0] + sc2[1] + sc2[2] + sc2[3];
        pkl[blk] = skl[0] + skl[1] + skl[2] + skl[3];
    }
}

// ---------------------------------------------------------------------------
// Kernel 3: finalize scalars. (unchanged)
// ---------------------------------------------------------------------------
__global__ __launch_bounds__(256) void finalize_kernel(
    const int* __restrict__ hist,
    const double* __restrict__ pc1, const double* __restrict__ pc2,
    const double* __restrict__ pkl,
    float* __restrict__ out)
{
    int t = threadIdx.x;
    int w = t >> 6, lane = t & 63;

    double a = 0.0, b = 0.0, c = 0.0;
    for (int i = t; i < 1024; i += 256) { a += pc1[i]; b += pc2[i]; c += pkl[i]; }

    float hm = 0.0f, hs = 0.0f;
    for (int k = t; k < KC; k += 256) {
        float p  = (float)hist[k]      * (1.0f / 32768.0f);
        hm += p * logf(p + 1e-10f);
        float p2 = (float)hist[KC + k] * (1.0f / 32768.0f);
        hs += p2 * logf(p2 + 1e-10f);
    }

    #pragma unroll
    for (int off = 1; off < 64; off <<= 1) {
        a  += __shfl_xor(a, off);
        b  += __shfl_xor(b, off);
        c  += __shfl_xor(c, off);
        hm += __shfl_xor(hm, off);
        hs += __shfl_xor(hs, off);
    }
    __shared__ double sa[4], sb[4], sc[4];
    __shared__ float  sm[4], ss[4];
    if (lane == 0) { sa[w] = a; sb[w] = b; sc[w] = c; sm[w] = hm; ss[w] = hs; }
    __syncthreads();
    if (t == 0) {
        double A = sa[0] + sa[1] + sa[2] + sa[3];
        double B = sb[0] + sb[1] + sb[2] + sb[3];
        double C = sc[0] + sc[1] + sc[2] + sc[3];
        float HM = sm[0] + sm[1] + sm[2] + sm[3];
        float HS = ss[0] + ss[1] + ss[2] + ss[3];
        float mean1 = (float)(A * (1.0 / 16777216.0));
        float mean2 = (float)(B * (1.0 / 16777216.0));
        float commitment = mean1 + mean2;
        float el = (float)(C * (1.0 / 32768.0));
        out[33554432] = commitment * 0.25f + el;   // vq_loss
        out[33554433] = expf(-HM);                 // perplexity_mean
        out[33554434] = expf(-HS);                 // perplexity_std
    }
}

// ---------------------------------------------------------------------------
extern "C" void kernel_launch(void* const* d_in, const int* in_sizes, int n_in,
                              void* d_out, int out_size, void* d_ws, size_t ws_size,
                              hipStream_t stream)
{
    const float* xmean = (const float*)d_in[0];
    const float* xstd  = (const float*)d_in[1];
    const float* emb   = (const float*)d_in[2];
    float* out = (float*)d_out;
    char*  ws  = (char*)d_ws;

    int*    inds = (int*)(ws + WS_INDS);
    int*    hist = (int*)(ws + WS_HIST);
    double* pc1  = (double*)(ws + WS_PC1);
    double* pc2  = (double*)(ws + WS_PC2);
    double* pkl  = (double*)(ws + WS_PKL);
    float*  xsq  = (float*)(ws + WS_XSQ);
    float*  esq  = (float*)(ws + WS_ESQ);
    unsigned short* ef16 = (unsigned short*)(ws + WS_EF16);

    const bool use_ef16 = (ws_size >= (size_t)WS_EF16_END);

    hipMemsetAsync(hist, 0, 2 * KC * sizeof(int), stream);

    rowsq_kernel<<<NROWSQ / 4, 256, 0, stream>>>(xmean, xsq, NROWSQ);
    rowsq_kernel<<<NROWSQ / 4, 256, 0, stream>>>(xstd, xsq + NROWSQ, NROWSQ);
    rowsq_kernel<<<KC / 4, 256, 0, stream>>>(emb, esq, KC);

    if (use_ef16) {
        cvt_e_tiled_kernel<<<KC * DDIM / 8 / 256, 256, 0, stream>>>(emb, ef16);
        mfma_argmin_kernel<true><<<RTOT / 128, 512, 0, stream>>>(
            xmean, xstd, emb, ef16, xsq, esq, inds);
    } else {
        mfma_argmin_kernel<false><<<RTOT / 128, 512, 0, stream>>>(
            xmean, xstd, emb, ef16, xsq, esq, inds);
    }

    gather_stats_kernel<<<1024, 256, 0, stream>>>(xmean, xstd, emb, inds,
                                                  out, out + (size_t)NROWSQ * DDIM,
                                                  hist, pc1, pc2, pkl);

    finalize_kernel<<<1, 256, 0, stream>>>(hist, pc1, pc2, pkl, out);
}

// Round 8
// 1304.569 us; speedup vs baseline: 3.1895x; 1.0404x over previous
//
#include <hip/hip_runtime.h>
#include <math.h>

#define NROWSQ 32768   // rows per input
#define RTOT   65536   // total rows (mean ++ std)
#define DDIM   512
#define KC     4096

#define CAP    32          // candidate list capacity per row
#define W_ACC  6.0f        // screen window in acc units (dist window = 6/4096 = 1.46e-3)
#define ESCALE 8192.0f     // 2^13, exact; keeps f16(e) out of denormal range

typedef __attribute__((ext_vector_type(8))) _Float16 half8;
typedef __attribute__((ext_vector_type(4))) float f32x4;

// ---- workspace layout (bytes) ----
#define WS_INDS 0               // 65536 * int
#define WS_HIST 262144          // 8192 * int
#define WS_PC1  294912          // 1024 * double
#define WS_PC2  303104          // 1024 * double
#define WS_PKL  311296          // 1024 * double
#define WS_XSQ  319488          // 65536 * float
#define WS_ESQ  581632          // 4096 * float
#define WS_EF16 598016          // 4096*512 * u16 (scaled f16 embedding, TILED layout)
#define WS_EF16_END (598016 + KC * DDIM * 2)

__device__ __forceinline__ uint2 pack4_f16(float4 v, float s) {
    _Float16 h0 = (_Float16)(v.x * s);
    _Float16 h1 = (_Float16)(v.y * s);
    _Float16 h2 = (_Float16)(v.z * s);
    _Float16 h3 = (_Float16)(v.w * s);
    uint2 r;
    r.x = (unsigned int)__builtin_bit_cast(unsigned short, h0)
        | ((unsigned int)__builtin_bit_cast(unsigned short, h1) << 16);
    r.y = (unsigned int)__builtin_bit_cast(unsigned short, h2)
        | ((unsigned int)__builtin_bit_cast(unsigned short, h3) << 16);
    return r;
}

__device__ __forceinline__ unsigned fkey(float f) {
    unsigned u = __float_as_uint(f);
    return u ^ ((unsigned)(((int)u) >> 31) | 0x80000000u);
}
__device__ __forceinline__ float fdecode(unsigned k) {
    return (k & 0x80000000u) ? __uint_as_float(k ^ 0x80000000u) : __uint_as_float(~k);
}

// ---------------------------------------------------------------------------
// Kernel 0: per-row sum of squares (f32), one wave per row.
// ---------------------------------------------------------------------------
__global__ __launch_bounds__(256) void rowsq_kernel(const float* __restrict__ src,
                                                    float* __restrict__ dst,
                                                    int nrows)
{
    int row  = blockIdx.x * 4 + (threadIdx.x >> 6);
    int lane = threadIdx.x & 63;
    if (row >= nrows) return;
    const float* p = src + (size_t)row * DDIM;
    float4 v1 = *(const float4*)&p[lane * 4];
    float4 v2 = *(const float4*)&p[256 + lane * 4];
    float s = v1.x*v1.x + v1.y*v1.y + v1.z*v1.z + v1.w*v1.w
            + v2.x*v2.x + v2.y*v2.y + v2.z*v2.z + v2.w*v2.w;
    #pragma unroll
    for (int off = 1; off < 64; off <<= 1) s += __shfl_xor(s, off);
    if (lane == 0) dst[row] = s;
}

// ---------------------------------------------------------------------------
// Kernel 0b: convert embedding to scaled f16 in TILED layout:
// slot(16B) = ct*8192 + chunk*512 + kslot*128 + code
//   where c = ct*128 + code (code row), d = chunk*32 + kslot*8 + 0..7
// ---------------------------------------------------------------------------
__global__ __launch_bounds__(256) void cvt_e_tiled_kernel(const float* __restrict__ emb,
                                                          unsigned short* __restrict__ ef)
{
    int i = blockIdx.x * 256 + threadIdx.x;   // 0..262143
    int c  = i >> 6;          // code 0..4095
    int dg = i & 63;          // 8-half d-group
    const float* p = &emb[(size_t)c * DDIM + dg * 8];
    float4 v0 = *(const float4*)p;
    float4 v1 = *(const float4*)(p + 4);
    uint2 p0 = pack4_f16(v0, ESCALE);
    uint2 p1 = pack4_f16(v1, ESCALE);
    uint4 pk; pk.x = p0.x; pk.y = p0.y; pk.z = p1.x; pk.w = p1.y;
    int ct = c >> 7, code = c & 127, chunk = dg >> 2, kslot = dg & 3;
    size_t slot = (size_t)ct * 8192 + chunk * 512 + kslot * 128 + code;
    *(uint4*)&ef[slot * 8] = pk;
}

// ---------------------------------------------------------------------------
// Kernel 1: A-resident (LDS) f16 MFMA screen, B direct global->VGPR with a
// DEPTH-4 register pipeline (8 loads in flight; compiler-counted vmcnt).
// NO barriers / NO inline asm in the hot loop. 512 threads, wave grid 2x4.
// Delayed candidate append + exact f32 rescore (bit-identical inds).
// ---------------------------------------------------------------------------
template<bool EF16>
__global__ __launch_bounds__(512, 1) void mfma_argmin_kernel(
    const float* __restrict__ xmean, const float* __restrict__ xstd,
    const float* __restrict__ emb, const unsigned short* __restrict__ ef,
    const float* __restrict__ xsq, const float* __restrict__ esq,
    int* __restrict__ inds)
{
    __shared__ unsigned short As[65536];      // 128KB: A f16, dg-major, XOR-swz
    __shared__ unsigned int   rowmax[128];
    __shared__ int            ccnt[128];
    __shared__ unsigned short cand[128 * CAP];
    __shared__ unsigned long long best[128];

    const int t    = threadIdx.x;
    const int lane = t & 63;
    const int wid  = t >> 6;                  // 0..7
    const int wr   = wid >> 2, wc = wid & 3;  // wave tile: 64 rows x 32 codes
    const int row0 = blockIdx.x * 128;
    const float* X = (row0 < NROWSQ) ? xmean : xstd;
    const int xrow0 = (row0 < NROWSQ) ? row0 : row0 - NROWSQ;

    if (t < 128) { rowmax[t] = 0u; ccnt[t] = 0; best[t] = ~0ull; }

    // B-frag base slot (16B units) within a chunk, for this lane:
    // slot = kslot*128 + code ; code = wc*32 + fc*16 + (lane&15)
    const int bo0 = ((lane >> 4) * 128) + wc * 32 + (lane & 15);   // fc=0
    const uint4* __restrict__ bptr = (const uint4*)ef;

    // ---- depth-4 B prologue: chunks 0..3 in flight before/during A staging --
    uint4 bpre[4][2];
    if (EF16) {
        #pragma unroll
        for (int p = 0; p < 4; ++p) {
            bpre[p][0] = bptr[(size_t)p * 512 + bo0];
            bpre[p][1] = bptr[(size_t)p * 512 + bo0 + 16];
        }
    }

    // ---- stage A once: 128 rows x 512 d, f32 -> f16, swizzled ----
    #pragma unroll 4
    for (int s = 0; s < 16; ++s) {
        int i   = t + s * 512;       // 0..8191
        int dg  = i & 63;            // 8-half d-group
        int row = i >> 6;
        const float* xp = &X[(size_t)(xrow0 + row) * DDIM + dg * 8];
        float4 v0 = *(const float4*)xp;
        float4 v1 = *(const float4*)(xp + 4);
        uint2 p0 = pack4_f16(v0, 1.0f);
        uint2 p1 = pack4_f16(v1, 1.0f);
        uint4 pk; pk.x = p0.x; pk.y = p0.y; pk.z = p1.x; pk.w = p1.y;
        int a16 = dg * 128 + (row ^ (dg & 7));
        *(uint4*)&As[a16 * 8] = pk;
    }
    __syncthreads();

    f32x4 accp[4][2];                // previous tile's finished accs
    #pragma unroll
    for (int fr = 0; fr < 4; ++fr)
        #pragma unroll
        for (int fc = 0; fc < 2; ++fc)
            accp[fr][fc] = (f32x4)(0.0f);

    for (int ct = 0; ct < 32; ++ct) {
        f32x4 acc[4][2];
        #pragma unroll
        for (int fr = 0; fr < 4; ++fr)
            #pragma unroll
            for (int fc = 0; fc < 2; ++fc)
                acc[fr][fc] = (f32x4)(0.0f);

        #pragma unroll
        for (int c = 0; c < 16; ++c) {
            const int g = ct * 16 + c;
            const int sl = c & 3;             // static after full unroll
            half8 bfrag[2];

            if (EF16) {
                bfrag[0] = __builtin_bit_cast(half8, bpre[sl][0]);
                bfrag[1] = __builtin_bit_cast(half8, bpre[sl][1]);
                int gn = g + 4; if (gn > 511) gn = 511;   // tail: harmless reload
                bpre[sl][0] = bptr[(size_t)gn * 512 + bo0];
                bpre[sl][1] = bptr[(size_t)gn * 512 + bo0 + 16];
            } else {
                // fallback: direct load + convert from f32 emb
                #pragma unroll
                for (int fc = 0; fc < 2; ++fc) {
                    int code = ct * 128 + wc * 32 + fc * 16 + (lane & 15);
                    const float* p = &emb[(size_t)code * DDIM + c * 32 + (lane >> 4) * 8];
                    float4 v0 = *(const float4*)p;
                    float4 v1 = *(const float4*)(p + 4);
                    uint2 p0 = pack4_f16(v0, ESCALE);
                    uint2 p1 = pack4_f16(v1, ESCALE);
                    uint4 pk; pk.x = p0.x; pk.y = p0.y; pk.z = p1.x; pk.w = p1.y;
                    bfrag[fc] = __builtin_bit_cast(half8, pk);
                }
            }

            half8 afrag[4];
            #pragma unroll
            for (int fr = 0; fr < 4; ++fr) {
                int ra = wr * 64 + fr * 16 + (lane & 15);
                int dg = c * 4 + (lane >> 4);
                int a16 = dg * 128 + (ra ^ (dg & 7));
                afrag[fr] = *(const half8*)&As[a16 * 8];
            }
            #pragma unroll
            for (int fr = 0; fr < 4; ++fr)
                #pragma unroll
                for (int fc = 0; fc < 2; ++fc)
                    acc[fr][fc] = __builtin_amdgcn_mfma_f32_16x16x32_f16(
                        afrag[fr], bfrag[fc], acc[fr][fc], 0, 0, 0);
        }

        // ---- update running row-max with THIS tile's accs (no barrier:
        //      races only make append thresholds more permissive -> sound) ----
        #pragma unroll
        for (int fr = 0; fr < 4; ++fr) {
            #pragma unroll
            for (int q = 0; q < 4; ++q) {
                float m = fmaxf(acc[fr][0][q], acc[fr][1][q]);
                int r = wr * 64 + fr * 16 + (lane >> 4) * 4 + q;
                unsigned k = fkey(m);
                if (k > rowmax[r]) atomicMax(&rowmax[r], k);
            }
        }

        // ---- delayed append: PREVIOUS tile's candidates vs tighter max ----
        if (ct > 0) {
            const int pct = ct - 1;
            #pragma unroll
            for (int fr = 0; fr < 4; ++fr) {
                #pragma unroll
                for (int q = 0; q < 4; ++q) {
                    int r = wr * 64 + fr * 16 + (lane >> 4) * 4 + q;
                    float thr = fdecode(rowmax[r]) - W_ACC;
                    #pragma unroll
                    for (int fc = 0; fc < 2; ++fc) {
                        if (accp[fr][fc][q] >= thr) {
                            int code = pct * 128 + wc * 32 + fc * 16 + (lane & 15);
                            int p = atomicAdd(&ccnt[r], 1);
                            if (p < CAP) cand[r * CAP + p] = (unsigned short)code;
                        }
                    }
                }
            }
        }
        #pragma unroll
        for (int fr = 0; fr < 4; ++fr)
            #pragma unroll
            for (int fc = 0; fc < 2; ++fc)
                accp[fr][fc] = acc[fr][fc];
    }

    // ---- append LAST tile (rowmax is final now) ----
    {
        const int pct = 31;
        #pragma unroll
        for (int fr = 0; fr < 4; ++fr) {
            #pragma unroll
            for (int q = 0; q < 4; ++q) {
                int r = wr * 64 + fr * 16 + (lane >> 4) * 4 + q;
                float thr = fdecode(rowmax[r]) - W_ACC;
                #pragma unroll
                for (int fc = 0; fc < 2; ++fc) {
                    if (accp[fr][fc][q] >= thr) {
                        int code = pct * 128 + wc * 32 + fc * 16 + (lane & 15);
                        int p = atomicAdd(&ccnt[r], 1);
                        if (p < CAP) cand[r * CAP + p] = (unsigned short)code;
                    }
                }
            }
        }
    }
    __syncthreads();

    // ---- exact f32 rescore of candidates (replicates round-1 fmaf chain) ----
    for (int e = t; e < 128 * CAP; e += 512) {
        int r = e >> 5, s = e & (CAP - 1);
        int cnt = ccnt[r]; if (cnt > CAP) cnt = CAP;
        if (s < cnt) {
            int c = cand[r * CAP + s];
            const float* xp = X   + (size_t)(xrow0 + r) * DDIM;
            const float* ep = emb + (size_t)c * DDIM;
            float acc2 = 0.0f;
            for (int d = 0; d < DDIM; d += 4) {
                float4 xv = *(const float4*)&xp[d];
                float4 ev = *(const float4*)&ep[d];
                acc2 = fmaf(xv.x, ev.x, acc2);
                acc2 = fmaf(xv.y, ev.y, acc2);
                acc2 = fmaf(xv.z, ev.z, acc2);
                acc2 = fmaf(xv.w, ev.w, acc2);
            }
            float dist = (xsq[row0 + r] + esq[c]) - 2.0f * acc2;
            unsigned long long key =
                ((unsigned long long)__float_as_uint(dist) << 32) | (unsigned)c;
            atomicMin(&best[r], key);
        }
    }
    __syncthreads();

    // ---- overflow fallback: full-row exact rescan (expected: never) ----
    for (int r = 0; r < 128; ++r) {
        if (ccnt[r] > CAP) {
            const float* xp = X + (size_t)(xrow0 + r) * DDIM;
            float xse = xsq[row0 + r];
            for (int c = t; c < KC; c += 512) {
                const float* ep = emb + (size_t)c * DDIM;
                float acc2 = 0.0f;
                #pragma unroll 8
                for (int d = 0; d < DDIM; d += 4) {
                    float4 xv = *(const float4*)&xp[d];
                    float4 ev = *(const float4*)&ep[d];
                    acc2 = fmaf(xv.x, ev.x, acc2);
                    acc2 = fmaf(xv.y, ev.y, acc2);
                    acc2 = fmaf(xv.z, ev.z, acc2);
                    acc2 = fmaf(xv.w, ev.w, acc2);
                }
                float dist = (xse + esq[c]) - 2.0f * acc2;
                unsigned long long key =
                    ((unsigned long long)__float_as_uint(dist) << 32) | (unsigned)c;
                atomicMin(&best[r], key);
            }
        }
    }
    __syncthreads();
    if (t < 128) inds[row0 + t] = (int)(unsigned)(best[t] & 0xffffffffull);
}

// ---------------------------------------------------------------------------
// Kernel 2: gather quantized rows + commitment/KL partials + hist. (unchanged)
// ---------------------------------------------------------------------------
__global__ __launch_bounds__(256) void gather_stats_kernel(
    const float* __restrict__ xmean, const float* __restrict__ xstd,
    const float* __restrict__ emb, const int* __restrict__ inds,
    float* __restrict__ out0, float* __restrict__ out1,
    int* __restrict__ hist,
    double* __restrict__ pc1, double* __restrict__ pc2, double* __restrict__ pkl)
{
    const int blk  = blockIdx.x;
    const int w    = threadIdx.x >> 6;
    const int lane = threadIdx.x & 63;

    float c1 = 0.0f, c2 = 0.0f, kls = 0.0f;

    for (int j = 0; j < 8; j++) {
        int n  = blk * 32 + j * 4 + w;
        int im = inds[n];
        int is = inds[NROWSQ + n];
        if (lane == 0) {
            atomicAdd(&hist[im], 1);
            atomicAdd(&hist[KC + is], 1);
        }
        const float* em = emb  + (size_t)im * DDIM;
        const float* es = emb  + (size_t)is * DDIM;
        const float* xm = xmean + (size_t)n * DDIM;
        const float* xv = xstd  + (size_t)n * DDIM;

        float t1 = 0.0f, t2 = 0.0f;
        float pp = 1.0f, pq = 1.0f;

        #pragma unroll
        for (int half = 0; half < 2; half++) {
            int d = half * 256 + lane * 4;
            float4 q4  = *(const float4*)&em[d];
            float4 m4  = *(const float4*)&xm[d];
            float4 qs4 = *(const float4*)&es[d];
            float4 s4  = *(const float4*)&xv[d];
            float qa[4] = {q4.x, q4.y, q4.z, q4.w};
            float ma[4] = {m4.x, m4.y, m4.z, m4.w};
            float qb[4] = {qs4.x, qs4.y, qs4.z, qs4.w};
            float sa[4] = {s4.x, s4.y, s4.z, s4.w};
            float o0[4], o1[4];
            #pragma unroll
            for (int u = 0; u < 4; u++) {
                float q = qa[u], m = ma[u], s = sa[u], qq = qb[u];
                o0[u] = m + (q - m);
                o1[u] = qq;
                float du = q - m;
                c1 += du * du;
                float dsv = qq - s; c2 += dsv * dsv;
                float sp = s * s, sq = qq * qq;
                float iq = 1.0f / sq;
                t1 += sp * iq;
                t2 += du * du * iq;
                pp *= sp; pq *= sq;
            }
            *(float4*)&out0[(size_t)n * DDIM + d] = make_float4(o0[0], o0[1], o0[2], o0[3]);
            *(float4*)&out1[(size_t)n * DDIM + d] = make_float4(o1[0], o1[1], o1[2], o1[3]);
        }

        #pragma unroll
        for (int off = 1; off < 64; off <<= 1) {
            t1 += __shfl_xor(t1, off);
            t2 += __shfl_xor(t2, off);
            pp *= __shfl_xor(pp, off);
            pq *= __shfl_xor(pq, off);
        }
        if (lane == 0) {
            float term4 = logf(pq + 1e-8f) - logf(pp + 1e-8f);
            float kl = 0.5f * (t1 + t2 - (float)DDIM + term4);
            float klc = kl < 0.0f ? 0.0f : (kl > 10.0f ? 10.0f : kl);
            kls += klc;
        }
    }

    #pragma unroll
    for (int off = 1; off < 64; off <<= 1) {
        c1 += __shfl_xor(c1, off);
        c2 += __shfl_xor(c2, off);
    }
    __shared__ double sc1[4], sc2[4], skl[4];
    if (lane == 0) { sc1[w] = (double)c1; sc2[w] = (double)c2; skl[w] = (double)kls; }
    __syncthreads();
    if (threadIdx.x == 0) {
        pc1[blk] = sc1[0] + sc1[1] + sc1[2] + sc1[3];
        pc2[blk] = sc2[0] + sc2[1] + sc2[2] + sc2[3];
        pkl[blk] = skl[0] + skl[1] + skl[2] + skl[3];
    }
}

// ---------------------------------------------------------------------------
// Kernel 3: finalize scalars. (unchanged)
// ---------------------------------------------------------------------------
__global__ __launch_bounds__(256) void finalize_kernel(
    const int* __restrict__ hist,
    const double* __restrict__ pc1, const double* __restrict__ pc2,
    const double* __restrict__ pkl,
    float* __restrict__ out)
{
    int t = threadIdx.x;
    int w = t >> 6, lane = t & 63;

    double a = 0.0, b = 0.0, c = 0.0;
    for (int i = t; i < 1024; i += 256) { a += pc1[i]; b += pc2[i]; c += pkl[i]; }

    float hm = 0.0f, hs = 0.0f;
    for (int k = t; k < KC; k += 256) {
        float p  = (float)hist[k]      * (1.0f / 32768.0f);
        hm += p * logf(p + 1e-10f);
        float p2 = (float)hist[KC + k] * (1.0f / 32768.0f);
        hs += p2 * logf(p2 + 1e-10f);
    }

    #pragma unroll
    for (int off = 1; off < 64; off <<= 1) {
        a  += __shfl_xor(a, off);
        b  += __shfl_xor(b, off);
        c  += __shfl_xor(c, off);
        hm += __shfl_xor(hm, off);
        hs += __shfl_xor(hs, off);
    }
    __shared__ double sa[4], sb[4], sc[4];
    __shared__ float  sm[4], ss[4];
    if (lane == 0) { sa[w] = a; sb[w] = b; sc[w] = c; sm[w] = hm; ss[w] = hs; }
    __syncthreads();
    if (t == 0) {
        double A = sa[0] + sa[1] + sa[2] + sa[3];
        double B = sb[0] + sb[1] + sb[2] + sb[3];
        double C = sc[0] + sc[1] + sc[2] + sc[3];
        float HM = sm[0] + sm[1] + sm[2] + sm[3];
        float HS = ss[0] + ss[1] + ss[2] + ss[3];
        float mean1 = (float)(A * (1.0 / 16777216.0));
        float mean2 = (float)(B * (1.0 / 16777216.0));
        float commitment = mean1 + mean2;
        float el = (float)(C * (1.0 / 32768.0));
        out[33554432] = commitment * 0.25f + el;   // vq_loss
        out[33554433] = expf(-HM);                 // perplexity_mean
        out[33554434] = expf(-HS);                 // perplexity_std
    }
}

// ---------------------------------------------------------------------------
extern "C" void kernel_launch(void* const* d_in, const int* in_sizes, int n_in,
                              void* d_out, int out_size, void* d_ws, size_t ws_size,
                              hipStream_t stream)
{
    const float* xmean = (const float*)d_in[0];
    const float* xstd  = (const float*)d_in[1];
    const float* emb   = (const float*)d_in[2];
    float* out = (float*)d_out;
    char*  ws  = (char*)d_ws;

    int*    inds = (int*)(ws + WS_INDS);
    int*    hist = (int*)(ws + WS_HIST);
    double* pc1  = (double*)(ws + WS_PC1);
    double* pc2  = (double*)(ws + WS_PC2);
    double* pkl  = (double*)(ws + WS_PKL);
    float*  xsq  = (float*)(ws + WS_XSQ);
    float*  esq  = (float*)(ws + WS_ESQ);
    unsigned short* ef16 = (unsigned short*)(ws + WS_EF16);

    const bool use_ef16 = (ws_size >= (size_t)WS_EF16_END);

    hipMemsetAsync(hist, 0, 2 * KC * sizeof(int), stream);

    rowsq_kernel<<<NROWSQ / 4, 256, 0, stream>>>(xmean, xsq, NROWSQ);
    rowsq_kernel<<<NROWSQ / 4, 256, 0, stream>>>(xstd, xsq + NROWSQ, NROWSQ);
    rowsq_kernel<<<KC / 4, 256, 0, stream>>>(emb, esq, KC);

    if (use_ef16) {
        cvt_e_tiled_kernel<<<KC * DDIM / 8 / 256, 256, 0, stream>>>(emb, ef16);
        mfma_argmin_kernel<true><<<RTOT / 128, 512, 0, stream>>>(
            xmean, xstd, emb, ef16, xsq, esq, inds);
    } else {
        mfma_argmin_kernel<false><<<RTOT / 128, 512, 0, stream>>>(
            xmean, xstd, emb, ef16, xsq, esq, inds);
    }

    gather_stats_kernel<<<1024, 256, 0, stream>>>(xmean, xstd, emb, inds,
                                                  out, out + (size_t)NROWSQ * DDIM,
                                                  hist, pc1, pc2, pkl);

    finalize_kernel<<<1, 256, 0, stream>>>(hist, pc1, pc2, pkl, out);
}